// Round 8
// baseline (465.183 us; speedup 1.0000x reference)
//
#include <hip/hip_runtime.h>

// LinearAttentionBlock on MI355X (gfx950)
// B=8, C=128, S=16384 (H=W=128), GROUPS=8
//
//   Q,K,V = xs @ W^T + b   (xs[b,s,c] = x[b,c,s])
//   softmax over s (no max needed: Q,K ~ N(0,1))
//   KVu[c,d] = sum_s exp(K[s,c]) V[s,d];  Zk[c] = sum_s exp(K);  Zq[c] = sum_s exp(Q)
//   KV2[c,d] = KVu[c,d] / (Zk[c] Zq[c]);  Z[s,d] = sum_c exp(Q[s,c]) KV2[c,d]
//   y = xs + Z;  out = GroupNorm(y) in flat [B,S,C] (== required output layout)
//
// R3: 64-row s-tiles for k_qkv/k_z (grid 2048, occupancy fix: was 17%/31% occ,
//     1.2-1.5 TB/s — latency-bound); k_tr vectorized stores; k_kv atomics halved.

#define Bn 8
#define Cn 128
#define Sn 16384
#define Gn 8

typedef float f32x4 __attribute__((ext_vector_type(4)));
typedef __bf16 bf16x8 __attribute__((ext_vector_type(8)));
typedef __bf16 bf16x4 __attribute__((ext_vector_type(4)));
typedef unsigned short u16;

__device__ __forceinline__ u16 f2bf(float f) {
    __bf16 h = (__bf16)f;
    return __builtin_bit_cast(u16, h);
}

// ---------------- K0: convert Wq/Wk/Wv fp32 -> bf16 ----------------
__global__ __launch_bounds__(256) void k_wconv(const float* __restrict__ Wq,
                                               const float* __restrict__ Wk,
                                               const float* __restrict__ Wv,
                                               u16* __restrict__ Wb) {
    int i = blockIdx.x * 256 + threadIdx.x;  // 0..49151
    const float* src = (i < 16384) ? Wq : (i < 32768 ? Wk : Wv);
    int j = i & 16383;
    Wb[i] = f2bf(src[j]);
}

// ---------------- K1: transpose x [B,C,S] fp32 -> XT [B,S,C] bf16 ----------------
// R3: float4 global reads, bf16x8 (16B) stores.
__global__ __launch_bounds__(256) void k_tr(const float* __restrict__ x, u16* __restrict__ XT) {
    __shared__ float t[64][65];
    const int b = blockIdx.z, c0 = blockIdx.y * 64, s0 = blockIdx.x * 64;
    const int tid = threadIdx.x;
    const float* xb = x + ((size_t)b * Cn + c0) * Sn + s0;
#pragma unroll
    for (int i = 0; i < 4; ++i) {
        int n = tid + i * 256;
        int cl = n >> 4, s4 = (n & 15) * 4;
        f32x4 v = *(const f32x4*)(xb + (size_t)cl * Sn + s4);
#pragma unroll
        for (int j = 0; j < 4; ++j) t[cl][s4 + j] = v[j];
    }
    __syncthreads();
    u16* xtb = XT + ((size_t)b * Sn + s0) * Cn + c0;
#pragma unroll
    for (int i = 0; i < 2; ++i) {
        int n = tid + i * 256;
        int sl = n >> 3, cl0 = (n & 7) * 8;
        bf16x8 o;
#pragma unroll
        for (int j = 0; j < 8; ++j) o[j] = (__bf16)t[cl0 + j][sl];
        *(bf16x8*)(xtb + sl * Cn + cl0) = o;
    }
}

// LDS tile helper: [rows][128 cols] bf16, 16B-chunk XOR swizzle (chunk ^= row&7)
__device__ __forceinline__ bf16x8 lds_frag128(const u16* lds, int row, int c_off) {
    int ch = c_off >> 3;
    return *(const bf16x8*)(&lds[row * Cn + ((ch ^ (row & 7)) << 3)]);
}

// ---------------- K2: QKV projections + exp + column sums ----------------
// R3: 64-s tile. grid (Sn/64, Bn), block 256 (4 waves).
__global__ __launch_bounds__(256) void k_qkv(
    const u16* __restrict__ XT, const u16* __restrict__ Wb,
    const float* __restrict__ bq, const float* __restrict__ bk, const float* __restrict__ bv,
    u16* __restrict__ EQ, u16* __restrict__ EK, u16* __restrict__ Vt,
    float* __restrict__ Zq, float* __restrict__ Zk) {
    __shared__ __align__(16) u16 tile[64 * 128];
    __shared__ float zbuf[4 * 128];
    const int b = blockIdx.y;
    const int s0 = blockIdx.x * 64;
    const int tid = threadIdx.x;
    const int w = tid >> 6, l = tid & 63;
    const int l15 = l & 15, lq = l >> 4;

    // stage XT tile [s_local 0..63][c] (chunk-swizzled)
    {
        const u16* g = XT + ((size_t)b * Sn + s0) * Cn;
#pragma unroll
        for (int i = 0; i < 4; ++i) {
            int n = tid + i * 256, row = n >> 4, ch = n & 15;
            bf16x8 v = *(const bf16x8*)(g + row * Cn + ch * 8);
            *(bf16x8*)(&tile[row * Cn + ((ch ^ (row & 7)) << 3)]) = v;
        }
    }
    __syncthreads();

    const u16* Wqb = Wb;
    const u16* Wkb = Wb + 16384;
    const u16* Wvb = Wb + 32768;

    // ===== Q pass: D[c'][s], A = Wq rows (c'), B = tile rows (s) =====
    {
        bf16x8 a[2][4];
#pragma unroll
        for (int m = 0; m < 2; ++m)
#pragma unroll
            for (int k = 0; k < 4; ++k) {
                int row = 32 * w + 16 * m + l15;
                a[m][k] = *(const bf16x8*)(Wqb + row * Cn + 32 * k + lq * 8);
            }
        f32x4 acc[2][4];
#pragma unroll
        for (int m = 0; m < 2; ++m)
#pragma unroll
            for (int n = 0; n < 4; ++n)
#pragma unroll
                for (int r = 0; r < 4; ++r) acc[m][n][r] = 0.f;
#pragma unroll
        for (int n = 0; n < 4; ++n)
#pragma unroll
            for (int k = 0; k < 4; ++k) {
                bf16x8 bf = lds_frag128(tile, 16 * n + l15, 32 * k + lq * 8);
                acc[0][n] = __builtin_amdgcn_mfma_f32_16x16x32_bf16(a[0][k], bf, acc[0][n], 0, 0, 0);
                acc[1][n] = __builtin_amdgcn_mfma_f32_16x16x32_bf16(a[1][k], bf, acc[1][n], 0, 0, 0);
            }
        float zq[2][4] = {};
        float bqv[2][4];
#pragma unroll
        for (int m = 0; m < 2; ++m)
#pragma unroll
            for (int r = 0; r < 4; ++r) bqv[m][r] = bq[32 * w + 16 * m + lq * 4 + r];
#pragma unroll
        for (int m = 0; m < 2; ++m) {
            int cp = 32 * w + 16 * m + lq * 4;
#pragma unroll
            for (int n = 0; n < 4; ++n) {
                int s = s0 + 16 * n + l15;
                bf16x4 pk;
#pragma unroll
                for (int r = 0; r < 4; ++r) {
                    float e = __expf(acc[m][n][r] + bqv[m][r]);
                    zq[m][r] += e;
                    pk[r] = (__bf16)e;
                }
                *(bf16x4*)(&EQ[((size_t)b * Sn + s) * Cn + cp]) = pk;
            }
        }
#pragma unroll
        for (int m = 0; m < 2; ++m)
#pragma unroll
            for (int r = 0; r < 4; ++r) {
                float v = zq[m][r];
                v += __shfl_xor(v, 1);
                v += __shfl_xor(v, 2);
                v += __shfl_xor(v, 4);
                v += __shfl_xor(v, 8);
                if (l15 == 0) atomicAdd(&Zq[b * Cn + 32 * w + 16 * m + lq * 4 + r], v);
            }
    }

    // ===== K and V passes: D[s][c'], A = tile rows (s, 16/wave), B = W rows (c') =====
    bf16x8 am[4];
#pragma unroll
    for (int k = 0; k < 4; ++k)
        am[k] = lds_frag128(tile, 16 * w + l15, 32 * k + lq * 8);

#pragma unroll
    for (int pass = 0; pass < 2; ++pass) {
        const u16* Wp = pass ? Wvb : Wkb;
        const float* bp = pass ? bv : bk;
        u16* Op = pass ? Vt : EK;
        f32x4 acc[8];
#pragma unroll
        for (int n = 0; n < 8; ++n)
#pragma unroll
            for (int r = 0; r < 4; ++r) acc[n][r] = 0.f;
        float bval[8];
#pragma unroll
        for (int n = 0; n < 8; ++n) bval[n] = bp[16 * n + l15];
#pragma unroll
        for (int n = 0; n < 8; ++n)
#pragma unroll
            for (int k = 0; k < 4; ++k) {
                bf16x8 bf = *(const bf16x8*)(Wp + (16 * n + l15) * Cn + 32 * k + lq * 8);
                acc[n] = __builtin_amdgcn_mfma_f32_16x16x32_bf16(am[k], bf, acc[n], 0, 0, 0);
            }
        float zk[8] = {};
        int sb = s0 + 16 * w + lq * 4;
#pragma unroll
        for (int n = 0; n < 8; ++n) {
            int cp = 16 * n + l15;
            bf16x4 pk;
#pragma unroll
            for (int r = 0; r < 4; ++r) {
                float e = acc[n][r] + bval[n];
                if (pass == 0) {
                    e = __expf(e);
                    zk[n] += e;
                }
                pk[r] = (__bf16)e;
            }
            *(bf16x4*)(&Op[((size_t)b * Cn + cp) * Sn + sb]) = pk;
        }
        if (pass == 0) {
            // reduce zk across lq (s-blocks) then stash per-wave; final atomics once.
#pragma unroll
            for (int n = 0; n < 8; ++n) {
                float v = zk[n];
                v += __shfl_xor(v, 16);
                v += __shfl_xor(v, 32);
                if (l < 16) zbuf[w * 128 + 16 * n + l] = v;
            }
        }
    }
    __syncthreads();
    if (tid < 128) {
        float v = zbuf[tid] + zbuf[128 + tid] + zbuf[256 + tid] + zbuf[384 + tid];
        atomicAdd(&Zk[b * Cn + tid], v);
    }
}

// ---------------- K3: KVu[c,d] = sum_s EK[c,s] * Vt[d,s] (split-S, atomics) ----------------
// R3: grid (16, Bn) — halves atomic lane-ops vs (32, Bn). block 512 (8 waves).
__global__ __launch_bounds__(512) void k_kv(const u16* __restrict__ EK, const u16* __restrict__ Vt,
                                            float* __restrict__ KVu) {
    __shared__ __align__(16) u16 ekt[128 * 64];
    __shared__ __align__(16) u16 vtt[128 * 64];
    const int b = blockIdx.y, sw = blockIdx.x;
    const int tid = threadIdx.x, w = tid >> 6, l = tid & 63;
    const int l15 = l & 15, lq = l >> 4;
    f32x4 acc[8];
#pragma unroll
    for (int n = 0; n < 8; ++n)
#pragma unroll
        for (int r = 0; r < 4; ++r) acc[n][r] = 0.f;
    const u16* ekb = EK + (size_t)b * Cn * Sn;
    const u16* vtb = Vt + (size_t)b * Cn * Sn;
    for (int step = 0; step < 16; ++step) {
        int s0 = sw * 1024 + step * 64;
        __syncthreads();
#pragma unroll
        for (int i = 0; i < 2; ++i) {
            int n = tid + i * 512, row = n >> 3, ch = n & 7;
            int lidx = row * 64 + ((ch ^ (row & 7)) << 3);
            *(bf16x8*)(&ekt[lidx]) = *(const bf16x8*)(ekb + (size_t)row * Sn + s0 + ch * 8);
            *(bf16x8*)(&vtt[lidx]) = *(const bf16x8*)(vtb + (size_t)row * Sn + s0 + ch * 8);
        }
        __syncthreads();
#pragma unroll
        for (int k = 0; k < 2; ++k) {
            int ach = 4 * k + lq;
            int arow = 16 * w + l15;
            bf16x8 af = *(const bf16x8*)(&ekt[arow * 64 + ((ach ^ (arow & 7)) << 3)]);
#pragma unroll
            for (int n = 0; n < 8; ++n) {
                int brow = 16 * n + l15;
                bf16x8 bf = *(const bf16x8*)(&vtt[brow * 64 + ((ach ^ (brow & 7)) << 3)]);
                acc[n] = __builtin_amdgcn_mfma_f32_16x16x32_bf16(af, bf, acc[n], 0, 0, 0);
            }
        }
    }
#pragma unroll
    for (int n = 0; n < 8; ++n)
#pragma unroll
        for (int r = 0; r < 4; ++r) {
            int c = 16 * w + lq * 4 + r, d = 16 * n + l15;
            atomicAdd(&KVu[((size_t)b * Cn + c) * Cn + d], acc[n][r]);
        }
}

// ---------------- K4: KV2T[d][c] = KVu[c][d] / (Zk[c]*Zq[c]), bf16 ----------------
__global__ __launch_bounds__(256) void k_kvnorm(const float* __restrict__ KVu,
                                                const float* __restrict__ Zq,
                                                const float* __restrict__ Zk,
                                                u16* __restrict__ KV2T) {
    __shared__ float zi[128];
    __shared__ u16 t[128 * 136];
    const int b = blockIdx.x, tid = threadIdx.x;
    if (tid < 128) zi[tid] = 1.f / (Zk[b * Cn + tid] * Zq[b * Cn + tid]);
    __syncthreads();
    for (int i = 0; i < 64; ++i) {
        int n = tid + i * 256, c = n >> 7, d = n & 127;
        t[c * 136 + d] = f2bf(KVu[((size_t)b * Cn + c) * Cn + d] * zi[c]);
    }
    __syncthreads();
    for (int i = 0; i < 64; ++i) {
        int n = tid + i * 256, d = n >> 7, c = n & 127;
        KV2T[((size_t)b * Cn + d) * Cn + c] = t[c * 136 + d];
    }
}

// ---------------- K5: Z + residual + GN stats ----------------
// R3: 64-s tile. grid (Sn/64, Bn), block 256.
__global__ __launch_bounds__(256) void k_z(
    const u16* __restrict__ EQ, const u16* __restrict__ KV2T, const u16* __restrict__ XT,
    u16* __restrict__ ybuf, float* __restrict__ gsum, float* __restrict__ gsq) {
    __shared__ __align__(16) u16 tile[64 * 128];
    const int b = blockIdx.y, s0 = blockIdx.x * 64;
    const int tid = threadIdx.x, w = tid >> 6, l = tid & 63;
    const int l15 = l & 15, lq = l >> 4;
    {
        const u16* g = EQ + ((size_t)b * Sn + s0) * Cn;
#pragma unroll
        for (int i = 0; i < 4; ++i) {
            int n = tid + i * 256, row = n >> 4, ch = n & 15;
            bf16x8 v = *(const bf16x8*)(g + row * Cn + ch * 8);
            *(bf16x8*)(&tile[row * Cn + ((ch ^ (row & 7)) << 3)]) = v;
        }
    }
    __syncthreads();
    bf16x8 a[2][4];
#pragma unroll
    for (int m = 0; m < 2; ++m)
#pragma unroll
        for (int k = 0; k < 4; ++k) {
            int rd = 32 * w + 16 * m + l15;
            a[m][k] = *(const bf16x8*)(KV2T + ((size_t)b * Cn + rd) * Cn + 32 * k + lq * 8);
        }
    f32x4 acc[2][4];
#pragma unroll
    for (int m = 0; m < 2; ++m)
#pragma unroll
        for (int n = 0; n < 4; ++n)
#pragma unroll
            for (int r = 0; r < 4; ++r) acc[m][n][r] = 0.f;
#pragma unroll
    for (int n = 0; n < 4; ++n)
#pragma unroll
        for (int k = 0; k < 4; ++k) {
            bf16x8 bf = lds_frag128(tile, 16 * n + l15, 32 * k + lq * 8);
            acc[0][n] = __builtin_amdgcn_mfma_f32_16x16x32_bf16(a[0][k], bf, acc[0][n], 0, 0, 0);
            acc[1][n] = __builtin_amdgcn_mfma_f32_16x16x32_bf16(a[1][k], bf, acc[1][n], 0, 0, 0);
        }
    float sm[2] = {0.f, 0.f}, sq[2] = {0.f, 0.f};
#pragma unroll
    for (int m = 0; m < 2; ++m) {
        int db = 32 * w + 16 * m + lq * 4;
#pragma unroll
        for (int n = 0; n < 4; ++n) {
            int s = s0 + 16 * n + l15;
            bf16x4 xv = *(const bf16x4*)(XT + ((size_t)b * Sn + s) * Cn + db);
            bf16x4 yk;
#pragma unroll
            for (int r = 0; r < 4; ++r) {
                float yv = (float)xv[r] + acc[m][n][r];
                sm[m] += yv;
                sq[m] += yv * yv;
                yk[r] = (__bf16)yv;
            }
            *(bf16x4*)(&ybuf[((size_t)b * Sn + s) * Cn + db]) = yk;
        }
    }
#pragma unroll
    for (int m = 0; m < 2; ++m) {
        float v1 = sm[m], v2 = sq[m];
#pragma unroll
        for (int mask = 1; mask < 64; mask <<= 1) {
            v1 += __shfl_xor(v1, mask);
            v2 += __shfl_xor(v2, mask);
        }
        if (l == 0) {
            int g = 2 * w + m;
            atomicAdd(&gsum[b * Gn + g], v1);
            atomicAdd(&gsq[b * Gn + g], v2);
        }
    }
}

// ---------------- K6: GroupNorm apply, write out (flat [B,S,C] fp32) ----------------
__global__ __launch_bounds__(256) void k_gn(const u16* __restrict__ ybuf,
                                            const float* __restrict__ gsum,
                                            const float* __restrict__ gsq,
                                            const float* __restrict__ gnw,
                                            const float* __restrict__ gnb,
                                            float* __restrict__ out) {
    const float invN = 1.f / (float)(16 * Sn);
    size_t idx = (size_t)blockIdx.x * 256 + threadIdx.x;  // 8-elem chunk id
    const size_t total = (size_t)Bn * Sn * Cn / 8;
    for (; idx < total; idx += (size_t)gridDim.x * 256) {
        size_t e0 = idx * 8;
        int c0 = (int)(e0 & 127);
        int b = (int)(e0 >> 21);  // / (Sn*Cn)
        int g = c0 >> 4;
        float mean = gsum[b * Gn + g] * invN;
        float var = gsq[b * Gn + g] * invN - mean * mean;
        float rstd = rsqrtf(var + 1e-5f);
        bf16x8 yv = *(const bf16x8*)(ybuf + e0);
        f32x4 o0, o1;
#pragma unroll
        for (int r = 0; r < 4; ++r) o0[r] = ((float)yv[r] - mean) * rstd * gnw[c0 + r] + gnb[c0 + r];
#pragma unroll
        for (int r = 0; r < 4; ++r) o1[r] = ((float)yv[4 + r] - mean) * rstd * gnw[c0 + 4 + r] + gnb[c0 + 4 + r];
        *(f32x4*)(out + e0) = o0;
        *(f32x4*)(out + e0 + 4) = o1;
    }
}

// ---------------- workspace layout (bytes) ----------------
static constexpr size_t XT_OFF = 0;                          // 32 MB bf16 [B,S,C]
static constexpr size_t EQ_OFF = 33554432;                   // 32 MB bf16 [B,S,C]
static constexpr size_t EK_OFF = 67108864;                   // 32 MB bf16 [B,C,S]  (ybuf aliases after K3)
static constexpr size_t VT_OFF = 100663296;                  // 32 MB bf16 [B,C,S]
static constexpr size_t WB_OFF = 134217728;                  // 96 KB bf16 Wq|Wk|Wv
static constexpr size_t KVU_OFF = WB_OFF + 98304;            // 512 KB fp32 [B,C,C]
static constexpr size_t ZQ_OFF = KVU_OFF + 524288;           // 4 KB
static constexpr size_t ZK_OFF = ZQ_OFF + 4096;              // 4 KB
static constexpr size_t GSUM_OFF = ZK_OFF + 4096;            // 256 B
static constexpr size_t GSQ_OFF = GSUM_OFF + 256;            // 256 B
static constexpr size_t KV2T_OFF = GSQ_OFF + 256;            // 256 KB bf16 [B,C,C] (transposed)
static constexpr size_t MEMSET_BYTES = 524288 + 4096 + 4096 + 256 + 256;

extern "C" void kernel_launch(void* const* d_in, const int* in_sizes, int n_in,
                              void* d_out, int out_size, void* d_ws, size_t ws_size,
                              hipStream_t stream) {
    const float* x = (const float*)d_in[0];
    const float* Wq = (const float*)d_in[1];
    const float* bq = (const float*)d_in[2];
    const float* Wk = (const float*)d_in[3];
    const float* bk = (const float*)d_in[4];
    const float* Wv = (const float*)d_in[5];
    const float* bv = (const float*)d_in[6];
    const float* gnw = (const float*)d_in[7];
    const float* gnb = (const float*)d_in[8];
    float* out = (float*)d_out;
    char* ws = (char*)d_ws;

    u16* XT = (u16*)(ws + XT_OFF);
    u16* EQ = (u16*)(ws + EQ_OFF);
    u16* EK = (u16*)(ws + EK_OFF);
    u16* Vt = (u16*)(ws + VT_OFF);
    u16* Wb = (u16*)(ws + WB_OFF);
    float* KVu = (float*)(ws + KVU_OFF);
    float* Zq = (float*)(ws + ZQ_OFF);
    float* Zk = (float*)(ws + ZK_OFF);
    float* Gsum = (float*)(ws + GSUM_OFF);
    float* Gsq = (float*)(ws + GSQ_OFF);
    u16* KV2T = (u16*)(ws + KV2T_OFF);
    u16* Ybuf = EK;  // alias: EK dead after k_kv

    hipMemsetAsync(ws + KVU_OFF, 0, MEMSET_BYTES, stream);
    k_wconv<<<dim3(192), dim3(256), 0, stream>>>(Wq, Wk, Wv, Wb);
    k_tr<<<dim3(Sn / 64, Cn / 64, Bn), dim3(256), 0, stream>>>(x, XT);
    k_qkv<<<dim3(Sn / 64, Bn), dim3(256), 0, stream>>>(XT, Wb, bq, bk, bv, EQ, EK, Vt, Zq, Zk);
    k_kv<<<dim3(16, Bn), dim3(512), 0, stream>>>(EK, Vt, KVu);
    k_kvnorm<<<dim3(Bn), dim3(256), 0, stream>>>(KVu, Zq, Zk, KV2T);
    k_z<<<dim3(Sn / 64, Bn), dim3(256), 0, stream>>>(EQ, KV2T, XT, Ybuf, Gsum, Gsq);
    k_gn<<<dim3(8192), dim3(256), 0, stream>>>(Ybuf, Gsum, Gsq, gnw, gnb, out);
}

// Round 9
// 320.060 us; speedup vs baseline: 1.4534x; 1.4534x over previous
//
#include <hip/hip_runtime.h>

// LinearAttentionBlock on MI355X (gfx950)
// B=8, C=128, S=16384 (H=W=128), GROUPS=8
//
//   Q,K,V = xs @ W^T + b   (xs[b,s,c] = x[b,c,s])
//   softmax over s (no max needed: Q,K ~ N(0,1))
//   KVu[c,d] = sum_s exp(K[s,c]) V[s,d];  Zk[c] = sum_s exp(K);  Zq[c] = sum_s exp(Q)
//   KV2[c,d] = KVu[c,d] / (Zk[c] Zq[c]);  Z[s,d] = sum_c exp(Q[s,c]) KV2[c,d]
//   y = xs + Z;  out = GroupNorm(y) in flat [B,S,C] (== required output layout)
//
// R8: REVERT to R0 128-row tiles (R3's 64-row tiles regressed 338->465us:
//     latency-chain-bound, not occupancy-bound — smaller tiles halved work per
//     fixed-latency chain). Kept: vectorized k_tr, zbuf Zk pre-reduce.
//     New: k_qkv m-split (VGPR 112 -> ~96); k_z 2 s-tiles/block (KV2T frags
//     loaded once, GN partials merged).

#define Bn 8
#define Cn 128
#define Sn 16384
#define Gn 8

typedef float f32x4 __attribute__((ext_vector_type(4)));
typedef __bf16 bf16x8 __attribute__((ext_vector_type(8)));
typedef __bf16 bf16x4 __attribute__((ext_vector_type(4)));
typedef unsigned short u16;

__device__ __forceinline__ u16 f2bf(float f) {
    __bf16 h = (__bf16)f;
    return __builtin_bit_cast(u16, h);
}

// ---------------- K0: convert Wq/Wk/Wv fp32 -> bf16 ----------------
__global__ __launch_bounds__(256) void k_wconv(const float* __restrict__ Wq,
                                               const float* __restrict__ Wk,
                                               const float* __restrict__ Wv,
                                               u16* __restrict__ Wb) {
    int i = blockIdx.x * 256 + threadIdx.x;  // 0..49151
    const float* src = (i < 16384) ? Wq : (i < 32768 ? Wk : Wv);
    int j = i & 16383;
    Wb[i] = f2bf(src[j]);
}

// ---------------- K1: transpose x [B,C,S] fp32 -> XT [B,S,C] bf16 ----------------
// vectorized: float4 global reads, bf16x8 (16B) stores. (validated correct R3 run)
__global__ __launch_bounds__(256) void k_tr(const float* __restrict__ x, u16* __restrict__ XT) {
    __shared__ float t[64][65];
    const int b = blockIdx.z, c0 = blockIdx.y * 64, s0 = blockIdx.x * 64;
    const int tid = threadIdx.x;
    const float* xb = x + ((size_t)b * Cn + c0) * Sn + s0;
#pragma unroll
    for (int i = 0; i < 4; ++i) {
        int n = tid + i * 256;
        int cl = n >> 4, s4 = (n & 15) * 4;
        f32x4 v = *(const f32x4*)(xb + (size_t)cl * Sn + s4);
#pragma unroll
        for (int j = 0; j < 4; ++j) t[cl][s4 + j] = v[j];
    }
    __syncthreads();
    u16* xtb = XT + ((size_t)b * Sn + s0) * Cn + c0;
#pragma unroll
    for (int i = 0; i < 2; ++i) {
        int n = tid + i * 256;
        int sl = n >> 3, cl0 = (n & 7) * 8;
        bf16x8 o;
#pragma unroll
        for (int j = 0; j < 8; ++j) o[j] = (__bf16)t[cl0 + j][sl];
        *(bf16x8*)(xtb + sl * Cn + cl0) = o;
    }
}

// LDS tile helper: [rows][128 cols] bf16, 16B-chunk XOR swizzle (chunk ^= row&7)
__device__ __forceinline__ bf16x8 lds_frag128(const u16* lds, int row, int c_off) {
    int ch = c_off >> 3;
    return *(const bf16x8*)(&lds[row * Cn + ((ch ^ (row & 7)) << 3)]);
}

// ---------------- K2: QKV projections + exp + column sums ----------------
// R8: 128-s tile (R0 geometry), m-split to cut live VGPRs (112 -> ~96).
// grid (Sn/128, Bn), block 256 (4 waves).
__global__ __launch_bounds__(256) void k_qkv(
    const u16* __restrict__ XT, const u16* __restrict__ Wb,
    const float* __restrict__ bq, const float* __restrict__ bk, const float* __restrict__ bv,
    u16* __restrict__ EQ, u16* __restrict__ EK, u16* __restrict__ Vt,
    float* __restrict__ Zq, float* __restrict__ Zk) {
    __shared__ __align__(16) u16 tile[128 * 128];
    __shared__ float zbuf[4 * 128];
    const int b = blockIdx.y;
    const int s0 = blockIdx.x * 128;
    const int tid = threadIdx.x;
    const int w = tid >> 6, l = tid & 63;
    const int l15 = l & 15, lq = l >> 4;

    // stage XT tile [s_local][c] (chunk-swizzled)
    {
        const u16* g = XT + ((size_t)b * Sn + s0) * Cn;
#pragma unroll
        for (int i = 0; i < 8; ++i) {
            int n = tid + i * 256, row = n >> 4, ch = n & 15;
            bf16x8 v = *(const bf16x8*)(g + row * Cn + ch * 8);
            *(bf16x8*)(&tile[row * Cn + ((ch ^ (row & 7)) << 3)]) = v;
        }
    }
    __syncthreads();

    const u16* Wqb = Wb;
    const u16* Wkb = Wb + 16384;
    const u16* Wvb = Wb + 32768;

    // ===== Q pass: D[c'][s], A = Wq rows (c'), B = tile rows (s); m-split =====
#pragma unroll
    for (int m = 0; m < 2; ++m) {
        const int arow = 32 * w + 16 * m + l15;
        bf16x8 a[4];
#pragma unroll
        for (int k = 0; k < 4; ++k) a[k] = *(const bf16x8*)(Wqb + arow * Cn + 32 * k + lq * 8);
        f32x4 acc[8];
#pragma unroll
        for (int n = 0; n < 8; ++n)
#pragma unroll
            for (int r = 0; r < 4; ++r) acc[n][r] = 0.f;
#pragma unroll
        for (int n = 0; n < 8; ++n)
#pragma unroll
            for (int k = 0; k < 4; ++k) {
                bf16x8 bf = lds_frag128(tile, 16 * n + l15, 32 * k + lq * 8);
                acc[n] = __builtin_amdgcn_mfma_f32_16x16x32_bf16(a[k], bf, acc[n], 0, 0, 0);
            }
        const int cp = 32 * w + 16 * m + lq * 4;
        float bqv[4];
#pragma unroll
        for (int r = 0; r < 4; ++r) bqv[r] = bq[cp + r];
        float zq[4] = {};
#pragma unroll
        for (int n = 0; n < 8; ++n) {
            int s = s0 + 16 * n + l15;
            bf16x4 pk;
#pragma unroll
            for (int r = 0; r < 4; ++r) {
                float e = __expf(acc[n][r] + bqv[r]);
                zq[r] += e;
                pk[r] = (__bf16)e;
            }
            *(bf16x4*)(&EQ[((size_t)b * Sn + s) * Cn + cp]) = pk;
        }
#pragma unroll
        for (int r = 0; r < 4; ++r) {
            float v = zq[r];
            v += __shfl_xor(v, 1);
            v += __shfl_xor(v, 2);
            v += __shfl_xor(v, 4);
            v += __shfl_xor(v, 8);
            if (l15 == 0) atomicAdd(&Zq[b * Cn + cp + r], v);
        }
    }

    // ===== K and V passes: D[s][c'], A = tile rows (s), B = W rows (c'); m-split =====
#pragma unroll
    for (int pass = 0; pass < 2; ++pass) {
        const u16* Wp = pass ? Wvb : Wkb;
        const float* bp = pass ? bv : bk;
        u16* Op = pass ? Vt : EK;
        float bval[8];
#pragma unroll
        for (int n = 0; n < 8; ++n) bval[n] = bp[16 * n + l15];
        float zk[8] = {};
#pragma unroll
        for (int m = 0; m < 2; ++m) {
            const int srow = 32 * w + 16 * m + l15;
            bf16x8 am[4];
#pragma unroll
            for (int k = 0; k < 4; ++k) am[k] = lds_frag128(tile, srow, 32 * k + lq * 8);
            f32x4 acc[8];
#pragma unroll
            for (int n = 0; n < 8; ++n)
#pragma unroll
                for (int r = 0; r < 4; ++r) acc[n][r] = 0.f;
#pragma unroll
            for (int n = 0; n < 8; ++n)
#pragma unroll
                for (int k = 0; k < 4; ++k) {
                    bf16x8 bf = *(const bf16x8*)(Wp + (16 * n + l15) * Cn + 32 * k + lq * 8);
                    acc[n] = __builtin_amdgcn_mfma_f32_16x16x32_bf16(am[k], bf, acc[n], 0, 0, 0);
                }
            const int sb = s0 + 32 * w + 16 * m + lq * 4;
#pragma unroll
            for (int n = 0; n < 8; ++n) {
                int cp = 16 * n + l15;
                bf16x4 pk;
#pragma unroll
                for (int r = 0; r < 4; ++r) {
                    float e = acc[n][r] + bval[n];
                    if (pass == 0) {
                        e = __expf(e);
                        zk[n] += e;
                    }
                    pk[r] = (__bf16)e;
                }
                *(bf16x4*)(&Op[((size_t)b * Cn + cp) * Sn + sb]) = pk;
            }
        }
        if (pass == 0) {
            // zk[n] holds lane-partial sums over this wave's 32 s-rows; reduce across lq.
#pragma unroll
            for (int n = 0; n < 8; ++n) {
                float v = zk[n];
                v += __shfl_xor(v, 16);
                v += __shfl_xor(v, 32);
                if (l < 16) zbuf[w * 128 + 16 * n + l] = v;
            }
        }
    }
    __syncthreads();
    if (tid < 128) {
        float v = zbuf[tid] + zbuf[128 + tid] + zbuf[256 + tid] + zbuf[384 + tid];
        atomicAdd(&Zk[b * Cn + tid], v);
    }
}

// ---------------- K3: KVu[c,d] = sum_s EK[c,s] * Vt[d,s] (split-S, atomics) ----------------
// R0 geometry (proven): grid (32, Bn), block 512 (8 waves), 8 steps of 64 s.
__global__ __launch_bounds__(512) void k_kv(const u16* __restrict__ EK, const u16* __restrict__ Vt,
                                            float* __restrict__ KVu) {
    __shared__ __align__(16) u16 ekt[128 * 64];
    __shared__ __align__(16) u16 vtt[128 * 64];
    const int b = blockIdx.y, sw = blockIdx.x;
    const int tid = threadIdx.x, w = tid >> 6, l = tid & 63;
    const int l15 = l & 15, lq = l >> 4;
    f32x4 acc[8];
#pragma unroll
    for (int n = 0; n < 8; ++n)
#pragma unroll
        for (int r = 0; r < 4; ++r) acc[n][r] = 0.f;
    const u16* ekb = EK + (size_t)b * Cn * Sn;
    const u16* vtb = Vt + (size_t)b * Cn * Sn;
    for (int step = 0; step < 8; ++step) {
        int s0 = sw * 512 + step * 64;
        __syncthreads();
#pragma unroll
        for (int i = 0; i < 2; ++i) {
            int n = tid + i * 512, row = n >> 3, ch = n & 7;
            int lidx = row * 64 + ((ch ^ (row & 7)) << 3);
            *(bf16x8*)(&ekt[lidx]) = *(const bf16x8*)(ekb + (size_t)row * Sn + s0 + ch * 8);
            *(bf16x8*)(&vtt[lidx]) = *(const bf16x8*)(vtb + (size_t)row * Sn + s0 + ch * 8);
        }
        __syncthreads();
#pragma unroll
        for (int k = 0; k < 2; ++k) {
            int ach = 4 * k + lq;
            int arow = 16 * w + l15;
            bf16x8 af = *(const bf16x8*)(&ekt[arow * 64 + ((ach ^ (arow & 7)) << 3)]);
#pragma unroll
            for (int n = 0; n < 8; ++n) {
                int brow = 16 * n + l15;
                bf16x8 bf = *(const bf16x8*)(&vtt[brow * 64 + ((ach ^ (brow & 7)) << 3)]);
                acc[n] = __builtin_amdgcn_mfma_f32_16x16x32_bf16(af, bf, acc[n], 0, 0, 0);
            }
        }
    }
#pragma unroll
    for (int n = 0; n < 8; ++n)
#pragma unroll
        for (int r = 0; r < 4; ++r) {
            int c = 16 * w + lq * 4 + r, d = 16 * n + l15;
            atomicAdd(&KVu[((size_t)b * Cn + c) * Cn + d], acc[n][r]);
        }
}

// ---------------- K4: KV2T[d][c] = KVu[c][d] / (Zk[c]*Zq[c]), bf16 ----------------
__global__ __launch_bounds__(256) void k_kvnorm(const float* __restrict__ KVu,
                                                const float* __restrict__ Zq,
                                                const float* __restrict__ Zk,
                                                u16* __restrict__ KV2T) {
    __shared__ float zi[128];
    __shared__ u16 t[128 * 136];
    const int b = blockIdx.x, tid = threadIdx.x;
    if (tid < 128) zi[tid] = 1.f / (Zk[b * Cn + tid] * Zq[b * Cn + tid]);
    __syncthreads();
    for (int i = 0; i < 64; ++i) {
        int n = tid + i * 256, c = n >> 7, d = n & 127;
        t[c * 136 + d] = f2bf(KVu[((size_t)b * Cn + c) * Cn + d] * zi[c]);
    }
    __syncthreads();
    for (int i = 0; i < 64; ++i) {
        int n = tid + i * 256, d = n >> 7, c = n & 127;
        KV2T[((size_t)b * Cn + d) * Cn + c] = t[c * 136 + d];
    }
}

// ---------------- K5: Z + residual + GN stats ----------------
// R8: 128-s tile (R0 geometry), TWO s-tiles per block — KV2T fragments loaded
// once, GN partials merged, half the prologues/atomics. grid (Sn/256, Bn).
__global__ __launch_bounds__(256) void k_z(
    const u16* __restrict__ EQ, const u16* __restrict__ KV2T, const u16* __restrict__ XT,
    u16* __restrict__ ybuf, float* __restrict__ gsum, float* __restrict__ gsq) {
    __shared__ __align__(16) u16 tile[128 * 128];
    const int b = blockIdx.y;
    const int tid = threadIdx.x, w = tid >> 6, l = tid & 63;
    const int l15 = l & 15, lq = l >> 4;

    // KV2T A-fragments: rows d = 32w+16m+l15, k-cols c — loaded once, reused both tiles.
    bf16x8 a[2][4];
#pragma unroll
    for (int m = 0; m < 2; ++m)
#pragma unroll
        for (int k = 0; k < 4; ++k) {
            int rd = 32 * w + 16 * m + l15;
            a[m][k] = *(const bf16x8*)(KV2T + ((size_t)b * Cn + rd) * Cn + 32 * k + lq * 8);
        }

    float sm[2] = {0.f, 0.f}, sq[2] = {0.f, 0.f};

    for (int t = 0; t < 2; ++t) {
        const int s0 = (blockIdx.x * 2 + t) * 128;
        if (t) __syncthreads();  // all waves done reading tile from previous iter
        {
            const u16* g = EQ + ((size_t)b * Sn + s0) * Cn;
#pragma unroll
            for (int i = 0; i < 8; ++i) {
                int n = tid + i * 256, row = n >> 4, ch = n & 15;
                bf16x8 v = *(const bf16x8*)(g + row * Cn + ch * 8);
                *(bf16x8*)(&tile[row * Cn + ((ch ^ (row & 7)) << 3)]) = v;
            }
        }
        __syncthreads();
        f32x4 acc[2][8];
#pragma unroll
        for (int m = 0; m < 2; ++m)
#pragma unroll
            for (int n = 0; n < 8; ++n)
#pragma unroll
                for (int r = 0; r < 4; ++r) acc[m][n][r] = 0.f;
#pragma unroll
        for (int n = 0; n < 8; ++n)
#pragma unroll
            for (int k = 0; k < 4; ++k) {
                bf16x8 bf = lds_frag128(tile, 16 * n + l15, 32 * k + lq * 8);
                acc[0][n] = __builtin_amdgcn_mfma_f32_16x16x32_bf16(a[0][k], bf, acc[0][n], 0, 0, 0);
                acc[1][n] = __builtin_amdgcn_mfma_f32_16x16x32_bf16(a[1][k], bf, acc[1][n], 0, 0, 0);
            }
#pragma unroll
        for (int m = 0; m < 2; ++m) {
            int db = 32 * w + 16 * m + lq * 4;
#pragma unroll
            for (int n = 0; n < 8; ++n) {
                int s = s0 + 16 * n + l15;
                bf16x4 xv = *(const bf16x4*)(XT + ((size_t)b * Sn + s) * Cn + db);
                bf16x4 yk;
#pragma unroll
                for (int r = 0; r < 4; ++r) {
                    float yv = (float)xv[r] + acc[m][n][r];
                    sm[m] += yv;
                    sq[m] += yv * yv;
                    yk[r] = (__bf16)yv;
                }
                *(bf16x4*)(&ybuf[((size_t)b * Sn + s) * Cn + db]) = yk;
            }
        }
    }

#pragma unroll
    for (int m = 0; m < 2; ++m) {
        float v1 = sm[m], v2 = sq[m];
#pragma unroll
        for (int mask = 1; mask < 64; mask <<= 1) {
            v1 += __shfl_xor(v1, mask);
            v2 += __shfl_xor(v2, mask);
        }
        if (l == 0) {
            int g = 2 * w + m;
            atomicAdd(&gsum[b * Gn + g], v1);
            atomicAdd(&gsq[b * Gn + g], v2);
        }
    }
}

// ---------------- K6: GroupNorm apply, write out (flat [B,S,C] fp32) ----------------
__global__ __launch_bounds__(256) void k_gn(const u16* __restrict__ ybuf,
                                            const float* __restrict__ gsum,
                                            const float* __restrict__ gsq,
                                            const float* __restrict__ gnw,
                                            const float* __restrict__ gnb,
                                            float* __restrict__ out) {
    const float invN = 1.f / (float)(16 * Sn);
    size_t idx = (size_t)blockIdx.x * 256 + threadIdx.x;  // 8-elem chunk id
    const size_t total = (size_t)Bn * Sn * Cn / 8;
    for (; idx < total; idx += (size_t)gridDim.x * 256) {
        size_t e0 = idx * 8;
        int c0 = (int)(e0 & 127);
        int b = (int)(e0 >> 21);  // / (Sn*Cn)
        int g = c0 >> 4;
        float mean = gsum[b * Gn + g] * invN;
        float var = gsq[b * Gn + g] * invN - mean * mean;
        float rstd = rsqrtf(var + 1e-5f);
        bf16x8 yv = *(const bf16x8*)(ybuf + e0);
        f32x4 o0, o1;
#pragma unroll
        for (int r = 0; r < 4; ++r) o0[r] = ((float)yv[r] - mean) * rstd * gnw[c0 + r] + gnb[c0 + r];
#pragma unroll
        for (int r = 0; r < 4; ++r) o1[r] = ((float)yv[4 + r] - mean) * rstd * gnw[c0 + 4 + r] + gnb[c0 + 4 + r];
        *(f32x4*)(out + e0) = o0;
        *(f32x4*)(out + e0 + 4) = o1;
    }
}

// ---------------- workspace layout (bytes) ----------------
static constexpr size_t XT_OFF = 0;                          // 32 MB bf16 [B,S,C]
static constexpr size_t EQ_OFF = 33554432;                   // 32 MB bf16 [B,S,C]
static constexpr size_t EK_OFF = 67108864;                   // 32 MB bf16 [B,C,S]  (ybuf aliases after K3)
static constexpr size_t VT_OFF = 100663296;                  // 32 MB bf16 [B,C,S]
static constexpr size_t WB_OFF = 134217728;                  // 96 KB bf16 Wq|Wk|Wv
static constexpr size_t KVU_OFF = WB_OFF + 98304;            // 512 KB fp32 [B,C,C]
static constexpr size_t ZQ_OFF = KVU_OFF + 524288;           // 4 KB
static constexpr size_t ZK_OFF = ZQ_OFF + 4096;              // 4 KB
static constexpr size_t GSUM_OFF = ZK_OFF + 4096;            // 256 B
static constexpr size_t GSQ_OFF = GSUM_OFF + 256;            // 256 B
static constexpr size_t KV2T_OFF = GSQ_OFF + 256;            // 256 KB bf16 [B,C,C] (transposed)
static constexpr size_t MEMSET_BYTES = 524288 + 4096 + 4096 + 256 + 256;

extern "C" void kernel_launch(void* const* d_in, const int* in_sizes, int n_in,
                              void* d_out, int out_size, void* d_ws, size_t ws_size,
                              hipStream_t stream) {
    const float* x = (const float*)d_in[0];
    const float* Wq = (const float*)d_in[1];
    const float* bq = (const float*)d_in[2];
    const float* Wk = (const float*)d_in[3];
    const float* bk = (const float*)d_in[4];
    const float* Wv = (const float*)d_in[5];
    const float* bv = (const float*)d_in[6];
    const float* gnw = (const float*)d_in[7];
    const float* gnb = (const float*)d_in[8];
    float* out = (float*)d_out;
    char* ws = (char*)d_ws;

    u16* XT = (u16*)(ws + XT_OFF);
    u16* EQ = (u16*)(ws + EQ_OFF);
    u16* EK = (u16*)(ws + EK_OFF);
    u16* Vt = (u16*)(ws + VT_OFF);
    u16* Wb = (u16*)(ws + WB_OFF);
    float* KVu = (float*)(ws + KVU_OFF);
    float* Zq = (float*)(ws + ZQ_OFF);
    float* Zk = (float*)(ws + ZK_OFF);
    float* Gsum = (float*)(ws + GSUM_OFF);
    float* Gsq = (float*)(ws + GSQ_OFF);
    u16* KV2T = (u16*)(ws + KV2T_OFF);
    u16* Ybuf = EK;  // alias: EK dead after k_kv

    hipMemsetAsync(ws + KVU_OFF, 0, MEMSET_BYTES, stream);
    k_wconv<<<dim3(192), dim3(256), 0, stream>>>(Wq, Wk, Wv, Wb);
    k_tr<<<dim3(Sn / 64, Cn / 64, Bn), dim3(256), 0, stream>>>(x, XT);
    k_qkv<<<dim3(Sn / 128, Bn), dim3(256), 0, stream>>>(XT, Wb, bq, bk, bv, EQ, EK, Vt, Zq, Zk);
    k_kv<<<dim3(32, Bn), dim3(512), 0, stream>>>(EK, Vt, KVu);
    k_kvnorm<<<dim3(Bn), dim3(256), 0, stream>>>(KVu, Zq, Zk, KV2T);
    k_z<<<dim3(Sn / 256, Bn), dim3(256), 0, stream>>>(EQ, KV2T, XT, Ybuf, Gsum, Gsq);
    k_gn<<<dim3(8192), dim3(256), 0, stream>>>(Ybuf, Gsum, Gsq, gnw, gnb, out);
}

// Round 11
// 287.025 us; speedup vs baseline: 1.6207x; 1.1151x over previous
//
#include <hip/hip_runtime.h>

// LinearAttentionBlock on MI355X (gfx950)
// B=8, C=128, S=16384 (H=W=128), GROUPS=8
//
//   Q,K,V = xs @ W^T + b   (xs[b,s,c] = x[b,c,s])
//   softmax over s (no max needed: Q,K ~ N(0,1))
//   KVu[c,d] = sum_s exp(K[s,c]) V[s,d];  Zk[c] = sum_s exp(K);  Zq[c] = sum_s exp(Q)
//   KV2[c,d] = KVu[c,d] / (Zk[c] Zq[c]);  Z[s,d] = sum_c exp(Q[s,c]) KV2[c,d]
//   y = xs + Z;  out = GroupNorm(y) in flat [B,S,C]
//
// R10: theory = store-transaction-bound (8B stores at 256B/32KB stride = 64
//      L2 txns per wave-store). k_qkv: revert R9 m-split (doubled LDS reads,
//      bank conflicts 655K->1.3M, 82->103us); add LDS-transpose epilogues ->
//      coalesced 16B stores for EQ/EK/Vt. k_z: keep 2-tile (R8 win); stage XT
//      + y through LDS, coalesced both directions.

#define Bn 8
#define Cn 128
#define Sn 16384
#define Gn 8

typedef float f32x4 __attribute__((ext_vector_type(4)));
typedef __bf16 bf16x8 __attribute__((ext_vector_type(8)));
typedef __bf16 bf16x4 __attribute__((ext_vector_type(4)));
typedef unsigned short u16;

__device__ __forceinline__ u16 f2bf(float f) {
    __bf16 h = (__bf16)f;
    return __builtin_bit_cast(u16, h);
}

// ---------------- K0: convert Wq/Wk/Wv fp32 -> bf16 ----------------
__global__ __launch_bounds__(256) void k_wconv(const float* __restrict__ Wq,
                                               const float* __restrict__ Wk,
                                               const float* __restrict__ Wv,
                                               u16* __restrict__ Wb) {
    int i = blockIdx.x * 256 + threadIdx.x;  // 0..49151
    const float* src = (i < 16384) ? Wq : (i < 32768 ? Wk : Wv);
    int j = i & 16383;
    Wb[i] = f2bf(src[j]);
}

// ---------------- K1: transpose x [B,C,S] fp32 -> XT [B,S,C] bf16 ----------------
__global__ __launch_bounds__(256) void k_tr(const float* __restrict__ x, u16* __restrict__ XT) {
    __shared__ float t[64][65];
    const int b = blockIdx.z, c0 = blockIdx.y * 64, s0 = blockIdx.x * 64;
    const int tid = threadIdx.x;
    const float* xb = x + ((size_t)b * Cn + c0) * Sn + s0;
#pragma unroll
    for (int i = 0; i < 4; ++i) {
        int n = tid + i * 256;
        int cl = n >> 4, s4 = (n & 15) * 4;
        f32x4 v = *(const f32x4*)(xb + (size_t)cl * Sn + s4);
#pragma unroll
        for (int j = 0; j < 4; ++j) t[cl][s4 + j] = v[j];
    }
    __syncthreads();
    u16* xtb = XT + ((size_t)b * Sn + s0) * Cn + c0;
#pragma unroll
    for (int i = 0; i < 2; ++i) {
        int n = tid + i * 256;
        int sl = n >> 3, cl0 = (n & 7) * 8;
        bf16x8 o;
#pragma unroll
        for (int j = 0; j < 8; ++j) o[j] = (__bf16)t[cl0 + j][sl];
        *(bf16x8*)(xtb + sl * Cn + cl0) = o;
    }
}

// LDS tile helpers: [128 rows][128 cols] bf16, 16B-chunk XOR swizzle (chunk ^= row&7)
__device__ __forceinline__ bf16x8 lds_frag128(const u16* lds, int row, int c_off) {
    int ch = c_off >> 3;
    return *(const bf16x8*)(&lds[row * Cn + ((ch ^ (row & 7)) << 3)]);
}
__device__ __forceinline__ int lds_addr8(int row, int col) {
    return row * Cn + ((((col >> 3) ^ (row & 7))) << 3) + (col & 7);
}
__device__ __forceinline__ void lds_write8(u16* lds, int row, int col, bf16x4 v) {
    *(bf16x4*)(&lds[lds_addr8(row, col)]) = v;
}
__device__ __forceinline__ bf16x4 lds_read8(const u16* lds, int row, int col) {
    return *(const bf16x4*)(&lds[lds_addr8(row, col)]);
}

// ---------------- K2: QKV projections + exp + column sums ----------------
// R10: R0 geometry (128-s tile, acc[2][8], am preloaded once) + LDS-transpose
// epilogues for coalesced 16B output stores. grid (Sn/128, Bn), block 256.
__global__ __launch_bounds__(256) void k_qkv(
    const u16* __restrict__ XT, const u16* __restrict__ Wb,
    const float* __restrict__ bq, const float* __restrict__ bk, const float* __restrict__ bv,
    u16* __restrict__ EQ, u16* __restrict__ EK, u16* __restrict__ Vt,
    float* __restrict__ Zq, float* __restrict__ Zk) {
    __shared__ __align__(16) u16 tile[128 * 128];
    __shared__ float zbuf[4 * 128];
    const int b = blockIdx.y;
    const int s0 = blockIdx.x * 128;
    const int tid = threadIdx.x;
    const int w = tid >> 6, l = tid & 63;
    const int l15 = l & 15, lq = l >> 4;

    // stage XT tile [s_local][c] (chunk-swizzled)
    {
        const u16* g = XT + ((size_t)b * Sn + s0) * Cn;
#pragma unroll
        for (int i = 0; i < 8; ++i) {
            int n = tid + i * 256, row = n >> 4, ch = n & 15;
            bf16x8 v = *(const bf16x8*)(g + row * Cn + ch * 8);
            *(bf16x8*)(&tile[row * Cn + ((ch ^ (row & 7)) << 3)]) = v;
        }
    }
    __syncthreads();

    const u16* Wqb = Wb;
    const u16* Wkb = Wb + 16384;
    const u16* Wvb = Wb + 32768;

    // preload K/V A-fragments (tile rows s) ONCE (R0 pattern)
    bf16x8 am[2][4];
#pragma unroll
    for (int m = 0; m < 2; ++m)
#pragma unroll
        for (int k = 0; k < 4; ++k)
            am[m][k] = lds_frag128(tile, 32 * w + 16 * m + l15, 32 * k + lq * 8);

    // ===== Q pass: D[c'][s] -> epilogue transposes to [s][c] =====
    {
        bf16x8 a[2][4];
#pragma unroll
        for (int m = 0; m < 2; ++m)
#pragma unroll
            for (int k = 0; k < 4; ++k) {
                int row = 32 * w + 16 * m + l15;
                a[m][k] = *(const bf16x8*)(Wqb + row * Cn + 32 * k + lq * 8);
            }
        f32x4 acc[2][8];
#pragma unroll
        for (int m = 0; m < 2; ++m)
#pragma unroll
            for (int n = 0; n < 8; ++n)
#pragma unroll
                for (int r = 0; r < 4; ++r) acc[m][n][r] = 0.f;
#pragma unroll
        for (int n = 0; n < 8; ++n)
#pragma unroll
            for (int k = 0; k < 4; ++k) {
                bf16x8 bf = lds_frag128(tile, 16 * n + l15, 32 * k + lq * 8);
                acc[0][n] = __builtin_amdgcn_mfma_f32_16x16x32_bf16(a[0][k], bf, acc[0][n], 0, 0, 0);
                acc[1][n] = __builtin_amdgcn_mfma_f32_16x16x32_bf16(a[1][k], bf, acc[1][n], 0, 0, 0);
            }
        float zq[2][4] = {};
        float bqv[2][4];
#pragma unroll
        for (int m = 0; m < 2; ++m)
#pragma unroll
            for (int r = 0; r < 4; ++r) bqv[m][r] = bq[32 * w + 16 * m + lq * 4 + r];
        bf16x4 pkq[2][8];
#pragma unroll
        for (int m = 0; m < 2; ++m)
#pragma unroll
            for (int n = 0; n < 8; ++n)
#pragma unroll
                for (int r = 0; r < 4; ++r) {
                    float e = __expf(acc[m][n][r] + bqv[m][r]);
                    zq[m][r] += e;
                    pkq[m][n][r] = (__bf16)e;
                }
#pragma unroll
        for (int m = 0; m < 2; ++m)
#pragma unroll
            for (int r = 0; r < 4; ++r) {
                float v = zq[m][r];
                v += __shfl_xor(v, 1);
                v += __shfl_xor(v, 2);
                v += __shfl_xor(v, 4);
                v += __shfl_xor(v, 8);
                if (l15 == 0) atomicAdd(&Zq[b * Cn + 32 * w + 16 * m + lq * 4 + r], v);
            }
        __syncthreads();  // all lanes done reading XT tile
        // stage Q results into tile as [s][c]
#pragma unroll
        for (int m = 0; m < 2; ++m) {
            int cp = 32 * w + 16 * m + lq * 4;
#pragma unroll
            for (int n = 0; n < 8; ++n) lds_write8(tile, 16 * n + l15, cp, pkq[m][n]);
        }
        __syncthreads();
        // coalesced 16B stores
        {
            u16* g = EQ + ((size_t)b * Sn + s0) * Cn;
#pragma unroll
            for (int i = 0; i < 8; ++i) {
                int n = tid + i * 256, row = n >> 4, ch = n & 15;
                bf16x8 v = *(const bf16x8*)(&tile[row * Cn + ((ch ^ (row & 7)) << 3)]);
                *(bf16x8*)(g + row * Cn + ch * 8) = v;
            }
        }
    }

    // ===== K and V passes: D[s][c'] -> epilogue to [c][s] coalesced =====
#pragma unroll
    for (int pass = 0; pass < 2; ++pass) {
        const u16* Wp = pass ? Wvb : Wkb;
        const float* bp = pass ? bv : bk;
        u16* Op = pass ? Vt : EK;
        f32x4 acc[2][8];
#pragma unroll
        for (int m = 0; m < 2; ++m)
#pragma unroll
            for (int n = 0; n < 8; ++n)
#pragma unroll
                for (int r = 0; r < 4; ++r) acc[m][n][r] = 0.f;
        float bval[8];
#pragma unroll
        for (int n = 0; n < 8; ++n) bval[n] = bp[16 * n + l15];
#pragma unroll
        for (int n = 0; n < 8; ++n)
#pragma unroll
            for (int k = 0; k < 4; ++k) {
                bf16x8 bf = *(const bf16x8*)(Wp + (16 * n + l15) * Cn + 32 * k + lq * 8);
                acc[0][n] = __builtin_amdgcn_mfma_f32_16x16x32_bf16(am[0][k], bf, acc[0][n], 0, 0, 0);
                acc[1][n] = __builtin_amdgcn_mfma_f32_16x16x32_bf16(am[1][k], bf, acc[1][n], 0, 0, 0);
            }
        float zk[8] = {};
        bf16x4 pk[2][8];
#pragma unroll
        for (int m = 0; m < 2; ++m)
#pragma unroll
            for (int n = 0; n < 8; ++n)
#pragma unroll
                for (int r = 0; r < 4; ++r) {
                    float e = acc[m][n][r] + bval[n];
                    if (pass == 0) {
                        e = __expf(e);
                        zk[n] += e;
                    }
                    pk[m][n][r] = (__bf16)e;
                }
        if (pass == 0) {
#pragma unroll
            for (int n = 0; n < 8; ++n) {
                float v = zk[n];
                v += __shfl_xor(v, 16);
                v += __shfl_xor(v, 32);
                if (l < 16) zbuf[w * 128 + 16 * n + l] = v;
            }
        }
        __syncthreads();  // previous epilogue's LDS reads done
        // stage results into tile as [c][s_local]
#pragma unroll
        for (int m = 0; m < 2; ++m) {
            int sl = 32 * w + 16 * m + lq * 4;
#pragma unroll
            for (int n = 0; n < 8; ++n) lds_write8(tile, 16 * n + l15, sl, pk[m][n]);
        }
        __syncthreads();
        // coalesced 16B stores: row = c, 128 s contiguous per row
#pragma unroll
        for (int i = 0; i < 8; ++i) {
            int n = tid + i * 256, row = n >> 4, ch = n & 15;
            bf16x8 v = *(const bf16x8*)(&tile[row * Cn + ((ch ^ (row & 7)) << 3)]);
            *(bf16x8*)(&Op[((size_t)b * Cn + row) * Sn + s0 + ch * 8]) = v;
        }
    }
    __syncthreads();
    if (tid < 128) {
        float v = zbuf[tid] + zbuf[128 + tid] + zbuf[256 + tid] + zbuf[384 + tid];
        atomicAdd(&Zk[b * Cn + tid], v);
    }
}

// ---------------- K3: KVu[c,d] = sum_s EK[c,s] * Vt[d,s] (split-S, atomics) ----------------
// R0 geometry (proven): grid (32, Bn), block 512 (8 waves), 8 steps of 64 s.
__global__ __launch_bounds__(512) void k_kv(const u16* __restrict__ EK, const u16* __restrict__ Vt,
                                            float* __restrict__ KVu) {
    __shared__ __align__(16) u16 ekt[128 * 64];
    __shared__ __align__(16) u16 vtt[128 * 64];
    const int b = blockIdx.y, sw = blockIdx.x;
    const int tid = threadIdx.x, w = tid >> 6, l = tid & 63;
    const int l15 = l & 15, lq = l >> 4;
    f32x4 acc[8];
#pragma unroll
    for (int n = 0; n < 8; ++n)
#pragma unroll
        for (int r = 0; r < 4; ++r) acc[n][r] = 0.f;
    const u16* ekb = EK + (size_t)b * Cn * Sn;
    const u16* vtb = Vt + (size_t)b * Cn * Sn;
    for (int step = 0; step < 8; ++step) {
        int s0 = sw * 512 + step * 64;
        __syncthreads();
#pragma unroll
        for (int i = 0; i < 2; ++i) {
            int n = tid + i * 512, row = n >> 3, ch = n & 7;
            int lidx = row * 64 + ((ch ^ (row & 7)) << 3);
            *(bf16x8*)(&ekt[lidx]) = *(const bf16x8*)(ekb + (size_t)row * Sn + s0 + ch * 8);
            *(bf16x8*)(&vtt[lidx]) = *(const bf16x8*)(vtb + (size_t)row * Sn + s0 + ch * 8);
        }
        __syncthreads();
#pragma unroll
        for (int k = 0; k < 2; ++k) {
            int ach = 4 * k + lq;
            int arow = 16 * w + l15;
            bf16x8 af = *(const bf16x8*)(&ekt[arow * 64 + ((ach ^ (arow & 7)) << 3)]);
#pragma unroll
            for (int n = 0; n < 8; ++n) {
                int brow = 16 * n + l15;
                bf16x8 bf = *(const bf16x8*)(&vtt[brow * 64 + ((ach ^ (brow & 7)) << 3)]);
                acc[n] = __builtin_amdgcn_mfma_f32_16x16x32_bf16(af, bf, acc[n], 0, 0, 0);
            }
        }
    }
#pragma unroll
    for (int n = 0; n < 8; ++n)
#pragma unroll
        for (int r = 0; r < 4; ++r) {
            int c = 16 * w + lq * 4 + r, d = 16 * n + l15;
            atomicAdd(&KVu[((size_t)b * Cn + c) * Cn + d], acc[n][r]);
        }
}

// ---------------- K4: KV2T[d][c] = KVu[c][d] / (Zk[c]*Zq[c]), bf16 ----------------
__global__ __launch_bounds__(256) void k_kvnorm(const float* __restrict__ KVu,
                                                const float* __restrict__ Zq,
                                                const float* __restrict__ Zk,
                                                u16* __restrict__ KV2T) {
    __shared__ float zi[128];
    __shared__ u16 t[128 * 136];
    const int b = blockIdx.x, tid = threadIdx.x;
    if (tid < 128) zi[tid] = 1.f / (Zk[b * Cn + tid] * Zq[b * Cn + tid]);
    __syncthreads();
    for (int i = 0; i < 64; ++i) {
        int n = tid + i * 256, c = n >> 7, d = n & 127;
        t[c * 136 + d] = f2bf(KVu[((size_t)b * Cn + c) * Cn + d] * zi[c]);
    }
    __syncthreads();
    for (int i = 0; i < 64; ++i) {
        int n = tid + i * 256, d = n >> 7, c = n & 127;
        KV2T[((size_t)b * Cn + d) * Cn + c] = t[c * 136 + d];
    }
}

// ---------------- K5: Z + residual + GN stats ----------------
// R10: 2 s-tiles/block (R8 win); XT staged through LDS (coalesced in),
// y written in-place in LDS, coalesced 16B store out. grid (Sn/256, Bn).
__global__ __launch_bounds__(256) void k_z(
    const u16* __restrict__ EQ, const u16* __restrict__ KV2T, const u16* __restrict__ XT,
    u16* __restrict__ ybuf, float* __restrict__ gsum, float* __restrict__ gsq) {
    __shared__ __align__(16) u16 tile[128 * 128];
    const int b = blockIdx.y;
    const int tid = threadIdx.x, w = tid >> 6, l = tid & 63;
    const int l15 = l & 15, lq = l >> 4;

    // KV2T A-fragments loaded once, reused for both s-tiles
    bf16x8 a[2][4];
#pragma unroll
    for (int m = 0; m < 2; ++m)
#pragma unroll
        for (int k = 0; k < 4; ++k) {
            int rd = 32 * w + 16 * m + l15;
            a[m][k] = *(const bf16x8*)(KV2T + ((size_t)b * Cn + rd) * Cn + 32 * k + lq * 8);
        }

    float sm[2] = {0.f, 0.f}, sq[2] = {0.f, 0.f};

    for (int t = 0; t < 2; ++t) {
        const int s0 = (blockIdx.x * 2 + t) * 128;
        if (t) __syncthreads();  // previous y-store LDS reads done
        // stage EQ tile
        {
            const u16* g = EQ + ((size_t)b * Sn + s0) * Cn;
#pragma unroll
            for (int i = 0; i < 8; ++i) {
                int n = tid + i * 256, row = n >> 4, ch = n & 15;
                bf16x8 v = *(const bf16x8*)(g + row * Cn + ch * 8);
                *(bf16x8*)(&tile[row * Cn + ((ch ^ (row & 7)) << 3)]) = v;
            }
        }
        __syncthreads();
        f32x4 acc[2][8];
#pragma unroll
        for (int m = 0; m < 2; ++m)
#pragma unroll
            for (int n = 0; n < 8; ++n)
#pragma unroll
                for (int r = 0; r < 4; ++r) acc[m][n][r] = 0.f;
#pragma unroll
        for (int n = 0; n < 8; ++n)
#pragma unroll
            for (int k = 0; k < 4; ++k) {
                bf16x8 bf = lds_frag128(tile, 16 * n + l15, 32 * k + lq * 8);
                acc[0][n] = __builtin_amdgcn_mfma_f32_16x16x32_bf16(a[0][k], bf, acc[0][n], 0, 0, 0);
                acc[1][n] = __builtin_amdgcn_mfma_f32_16x16x32_bf16(a[1][k], bf, acc[1][n], 0, 0, 0);
            }
        __syncthreads();  // done reading EQ tile
        // stage XT tile (coalesced), then lane-local y = x + z in LDS
        {
            const u16* g = XT + ((size_t)b * Sn + s0) * Cn;
#pragma unroll
            for (int i = 0; i < 8; ++i) {
                int n = tid + i * 256, row = n >> 4, ch = n & 15;
                bf16x8 v = *(const bf16x8*)(g + row * Cn + ch * 8);
                *(bf16x8*)(&tile[row * Cn + ((ch ^ (row & 7)) << 3)]) = v;
            }
        }
        __syncthreads();
#pragma unroll
        for (int m = 0; m < 2; ++m) {
            int db = 32 * w + 16 * m + lq * 4;
#pragma unroll
            for (int n = 0; n < 8; ++n) {
                int row = 16 * n + l15;
                bf16x4 xv = lds_read8(tile, row, db);
                bf16x4 yk;
#pragma unroll
                for (int r = 0; r < 4; ++r) {
                    float yv = (float)xv[r] + acc[m][n][r];
                    sm[m] += yv;
                    sq[m] += yv * yv;
                    yk[r] = (__bf16)yv;
                }
                lds_write8(tile, row, db, yk);  // in-place: same lane, same slot
            }
        }
        __syncthreads();
        // coalesced 16B store y tile -> ybuf
        {
            u16* g = ybuf + ((size_t)b * Sn + s0) * Cn;
#pragma unroll
            for (int i = 0; i < 8; ++i) {
                int n = tid + i * 256, row = n >> 4, ch = n & 15;
                bf16x8 v = *(const bf16x8*)(&tile[row * Cn + ((ch ^ (row & 7)) << 3)]);
                *(bf16x8*)(g + row * Cn + ch * 8) = v;
            }
        }
    }

#pragma unroll
    for (int m = 0; m < 2; ++m) {
        float v1 = sm[m], v2 = sq[m];
#pragma unroll
        for (int mask = 1; mask < 64; mask <<= 1) {
            v1 += __shfl_xor(v1, mask);
            v2 += __shfl_xor(v2, mask);
        }
        if (l == 0) {
            int g = 2 * w + m;
            atomicAdd(&gsum[b * Gn + g], v1);
            atomicAdd(&gsq[b * Gn + g], v2);
        }
    }
}

// ---------------- K6: GroupNorm apply, write out (flat [B,S,C] fp32) ----------------
__global__ __launch_bounds__(256) void k_gn(const u16* __restrict__ ybuf,
                                            const float* __restrict__ gsum,
                                            const float* __restrict__ gsq,
                                            const float* __restrict__ gnw,
                                            const float* __restrict__ gnb,
                                            float* __restrict__ out) {
    const float invN = 1.f / (float)(16 * Sn);
    size_t idx = (size_t)blockIdx.x * 256 + threadIdx.x;  // 8-elem chunk id
    const size_t total = (size_t)Bn * Sn * Cn / 8;
    for (; idx < total; idx += (size_t)gridDim.x * 256) {
        size_t e0 = idx * 8;
        int c0 = (int)(e0 & 127);
        int b = (int)(e0 >> 21);  // / (Sn*Cn)
        int g = c0 >> 4;
        float mean = gsum[b * Gn + g] * invN;
        float var = gsq[b * Gn + g] * invN - mean * mean;
        float rstd = rsqrtf(var + 1e-5f);
        bf16x8 yv = *(const bf16x8*)(ybuf + e0);
        f32x4 o0, o1;
#pragma unroll
        for (int r = 0; r < 4; ++r) o0[r] = ((float)yv[r] - mean) * rstd * gnw[c0 + r] + gnb[c0 + r];
#pragma unroll
        for (int r = 0; r < 4; ++r) o1[r] = ((float)yv[4 + r] - mean) * rstd * gnw[c0 + 4 + r] + gnb[c0 + 4 + r];
        *(f32x4*)(out + e0) = o0;
        *(f32x4*)(out + e0 + 4) = o1;
    }
}

// ---------------- workspace layout (bytes) ----------------
static constexpr size_t XT_OFF = 0;                          // 32 MB bf16 [B,S,C]
static constexpr size_t EQ_OFF = 33554432;                   // 32 MB bf16 [B,S,C]
static constexpr size_t EK_OFF = 67108864;                   // 32 MB bf16 [B,C,S]  (ybuf aliases after K3)
static constexpr size_t VT_OFF = 100663296;                  // 32 MB bf16 [B,C,S]
static constexpr size_t WB_OFF = 134217728;                  // 96 KB bf16 Wq|Wk|Wv
static constexpr size_t KVU_OFF = WB_OFF + 98304;            // 512 KB fp32 [B,C,C]
static constexpr size_t ZQ_OFF = KVU_OFF + 524288;           // 4 KB
static constexpr size_t ZK_OFF = ZQ_OFF + 4096;              // 4 KB
static constexpr size_t GSUM_OFF = ZK_OFF + 4096;            // 256 B
static constexpr size_t GSQ_OFF = GSUM_OFF + 256;            // 256 B
static constexpr size_t KV2T_OFF = GSQ_OFF + 256;            // 256 KB bf16 [B,C,C] (transposed)
static constexpr size_t MEMSET_BYTES = 524288 + 4096 + 4096 + 256 + 256;

extern "C" void kernel_launch(void* const* d_in, const int* in_sizes, int n_in,
                              void* d_out, int out_size, void* d_ws, size_t ws_size,
                              hipStream_t stream) {
    const float* x = (const float*)d_in[0];
    const float* Wq = (const float*)d_in[1];
    const float* bq = (const float*)d_in[2];
    const float* Wk = (const float*)d_in[3];
    const float* bk = (const float*)d_in[4];
    const float* Wv = (const float*)d_in[5];
    const float* bv = (const float*)d_in[6];
    const float* gnw = (const float*)d_in[7];
    const float* gnb = (const float*)d_in[8];
    float* out = (float*)d_out;
    char* ws = (char*)d_ws;

    u16* XT = (u16*)(ws + XT_OFF);
    u16* EQ = (u16*)(ws + EQ_OFF);
    u16* EK = (u16*)(ws + EK_OFF);
    u16* Vt = (u16*)(ws + VT_OFF);
    u16* Wb = (u16*)(ws + WB_OFF);
    float* KVu = (float*)(ws + KVU_OFF);
    float* Zq = (float*)(ws + ZQ_OFF);
    float* Zk = (float*)(ws + ZK_OFF);
    float* Gsum = (float*)(ws + GSUM_OFF);
    float* Gsq = (float*)(ws + GSQ_OFF);
    u16* KV2T = (u16*)(ws + KV2T_OFF);
    u16* Ybuf = EK;  // alias: EK dead after k_kv

    hipMemsetAsync(ws + KVU_OFF, 0, MEMSET_BYTES, stream);
    k_wconv<<<dim3(192), dim3(256), 0, stream>>>(Wq, Wk, Wv, Wb);
    k_tr<<<dim3(Sn / 64, Cn / 64, Bn), dim3(256), 0, stream>>>(x, XT);
    k_qkv<<<dim3(Sn / 128, Bn), dim3(256), 0, stream>>>(XT, Wb, bq, bk, bv, EQ, EK, Vt, Zq, Zk);
    k_kv<<<dim3(32, Bn), dim3(512), 0, stream>>>(EK, Vt, KVu);
    k_kvnorm<<<dim3(Bn), dim3(256), 0, stream>>>(KVu, Zq, Zk, KV2T);
    k_z<<<dim3(Sn / 256, Bn), dim3(256), 0, stream>>>(EQ, KV2T, XT, Ybuf, Gsum, Gsq);
    k_gn<<<dim3(8192), dim3(256), 0, stream>>>(Ybuf, Gsum, Gsq, gnw, gnb, out);
}